// Round 1
// baseline (16562.810 us; speedup 1.0000x reference)
//
#include <hip/hip_runtime.h>

#define T_STEPS 512
#define B_SZ    128
#define H_SZ    1024

typedef __bf16 bf16x8 __attribute__((ext_vector_type(8)));
typedef float  f32x4  __attribute__((ext_vector_type(4)));
typedef float  f32x2  __attribute__((ext_vector_type(2)));

__device__ __forceinline__ void split_bf16(float x, __bf16& hi, __bf16& lo) {
  hi = (__bf16)x;
  lo = (__bf16)(x - (float)hi);
}

// 256 WGs x 256 threads, persistent. 8 groups (16 batches each) x 32 column
// slices (32 cols each). W_hh slice lives in VGPRs as pre-split bf16 B-frags.
__global__ __launch_bounds__(256, 1)
void rnn_scan_kernel(const float* __restrict__ inputs,
                     const float* __restrict__ init_state,
                     const float* __restrict__ noise,
                     const float* __restrict__ wih,
                     const float* __restrict__ whh,
                     const float* __restrict__ bias,
                     float* __restrict__ out,
                     unsigned int* __restrict__ flags) {
  constexpr float kAlpha = 0.2f;
  constexpr float kBeta  = 0.8f;
  constexpr float kSigma = 0.15811388300841897f;  // sqrt(2/alpha)*0.05

  const int wg   = blockIdx.x;
  const int g    = wg & 7;    // group: blockIdx%8 -> XCD-affine if round-robin
  const int s    = wg >> 3;   // column slice 0..31
  const int b0   = g << 4;    // first batch of group
  const int j0   = s << 5;    // first column of slice
  const int tid  = threadIdx.x;
  const int wave = tid >> 6;
  const int lane = tid & 63;
  const int jn   = lane & 15;         // MFMA m/n lane index
  const int kq   = (lane >> 4) << 3;  // MFMA k quad offset 0/8/16/24

  __shared__ float cred[4][2][16][17];  // per-wave partial C, padded

  // update-phase mapping: thread -> (batch b_l, column pair jp)
  const int b_l = tid >> 4;
  const int jp  = tid & 15;
  const int jj  = j0 + (jp << 1);
  const int gb  = b0 + b_l;

  const float w0e = wih[jj],        w0o = wih[jj + 1];
  const float w1e = wih[H_SZ + jj], w1o = wih[H_SZ + jj + 1];
  const float be  = bias[jj],       bo  = bias[jj + 1];

  // state kept in registers for this thread's two elements
  float he = init_state[gb * H_SZ + jj];
  float ho = init_state[gb * H_SZ + jj + 1];
  { f32x2 v; v[0] = he; v[1] = ho; *(f32x2*)&out[gb * H_SZ + jj] = v; }

  // ---- build static B fragments: W_hh[k in wave's 256-range][32 cols] ----
  bf16x8 Bh[8][2], Bl[8][2];
  #pragma unroll
  for (int i = 0; i < 8; ++i) {
    const int kb = (wave << 8) + (i << 5) + kq;
    #pragma unroll
    for (int jt = 0; jt < 2; ++jt) {
      const int jc = j0 + (jt << 4) + jn;
      bf16x8 vh, vl;
      #pragma unroll
      for (int u = 0; u < 8; ++u) {
        const float wv = whh[(kb + u) * H_SZ + jc];
        __bf16 hh, ll; split_bf16(wv, hh, ll);
        vh[u] = hh; vl[u] = ll;
      }
      Bh[i][jt] = vh; Bl[i][jt] = vl;
    }
  }

  __syncthreads();  // drains vmcnt: row-0 stores done
  if (tid == 0) {
    __threadfence();
    __hip_atomic_store(&flags[(g << 5) + s], 1u,
                       __ATOMIC_RELEASE, __HIP_MEMORY_SCOPE_AGENT);
  }

  const size_t BH = (size_t)B_SZ * H_SZ;

  for (int t = 0; t < T_STEPS; ++t) {
    // prefetch drive operands (state-independent) before the sync point
    f32x2 nz  = *(const f32x2*)&noise[t * BH + gb * H_SZ + jj];
    f32x2 inp = *(const f32x2*)&inputs[(t * B_SZ + gb) * 2];

    // wait for all 32 slices of state t (flags are monotonic step counters)
    {
      const unsigned int target = (unsigned int)(t + 1);
      int spins = 0;
      bool ok;
      do {
        unsigned int v = target;
        if (lane < 32)
          v = __hip_atomic_load(&flags[(g << 5) + lane],
                                __ATOMIC_RELAXED, __HIP_MEMORY_SCOPE_AGENT);
        ok = __all(v >= target);
        if (!ok) { __builtin_amdgcn_s_sleep(1); if (++spins > (1 << 24)) break; }
      } while (!ok);
    }
    __threadfence();  // acquire: invalidate caches before reading remote state

    // ---- MFMA over this wave's K quarter: out[16,32] partial ----
    f32x4 acc0 = {0.f, 0.f, 0.f, 0.f}, acc1 = {0.f, 0.f, 0.f, 0.f};
    const float* arow = out + t * BH + (size_t)(b0 + jn) * H_SZ + (wave << 8) + kq;
    #pragma unroll
    for (int i = 0; i < 8; ++i) {
      f32x4 v0 = *(const f32x4*)(arow + (i << 5));
      f32x4 v1 = *(const f32x4*)(arow + (i << 5) + 4);
      bf16x8 ah, al;
      #pragma unroll
      for (int u = 0; u < 4; ++u) {
        const float r0 = fmaxf(v0[u], 0.f);
        const float r1 = fmaxf(v1[u], 0.f);
        __bf16 h0, l0, h1, l1;
        split_bf16(r0, h0, l0); split_bf16(r1, h1, l1);
        ah[u] = h0; al[u] = l0; ah[u + 4] = h1; al[u + 4] = l1;
      }
      acc0 = __builtin_amdgcn_mfma_f32_16x16x32_bf16(ah, Bh[i][0], acc0, 0, 0, 0);
      acc1 = __builtin_amdgcn_mfma_f32_16x16x32_bf16(ah, Bh[i][1], acc1, 0, 0, 0);
      acc0 = __builtin_amdgcn_mfma_f32_16x16x32_bf16(al, Bh[i][0], acc0, 0, 0, 0);
      acc1 = __builtin_amdgcn_mfma_f32_16x16x32_bf16(al, Bh[i][1], acc1, 0, 0, 0);
      acc0 = __builtin_amdgcn_mfma_f32_16x16x32_bf16(ah, Bl[i][0], acc0, 0, 0, 0);
      acc1 = __builtin_amdgcn_mfma_f32_16x16x32_bf16(ah, Bl[i][1], acc1, 0, 0, 0);
    }

    // ---- 4-wave reduction via LDS ----
    #pragma unroll
    for (int r = 0; r < 4; ++r) {
      const int br = ((lane >> 4) << 2) + r;  // C row = batch
      cred[wave][0][br][jn] = acc0[r];
      cred[wave][1][br][jn] = acc1[r];
    }
    __syncthreads();

    // ---- state update for this thread's (b_l, jj/jj+1) ----
    const int jt = jp >> 3;
    const int c0 = (jp << 1) & 15;
    const float accE = cred[0][jt][b_l][c0]     + cred[1][jt][b_l][c0]
                     + cred[2][jt][b_l][c0]     + cred[3][jt][b_l][c0];
    const float accO = cred[0][jt][b_l][c0 + 1] + cred[1][jt][b_l][c0 + 1]
                     + cred[2][jt][b_l][c0 + 1] + cred[3][jt][b_l][c0 + 1];
    const float de = fmaf(inp[0], w0e, fmaf(inp[1], w1e, fmaf(kSigma, nz[0], be)));
    const float dq = fmaf(inp[0], w0o, fmaf(inp[1], w1o, fmaf(kSigma, nz[1], bo)));
    he = kBeta * he + kAlpha * (accE + de);
    ho = kBeta * ho + kAlpha * (accO + dq);
    { f32x2 v; v[0] = he; v[1] = ho;
      *(f32x2*)&out[(t + 1) * BH + gb * H_SZ + jj] = v; }

    __syncthreads();  // all d_out stores of this WG drained (vmcnt) + cred reads done
    if (tid == 0) {
      __threadfence();  // release: push L2 so other XCDs see the state row
      __hip_atomic_store(&flags[(g << 5) + s], (unsigned int)(t + 2),
                         __ATOMIC_RELEASE, __HIP_MEMORY_SCOPE_AGENT);
    }
  }
}

extern "C" void kernel_launch(void* const* d_in, const int* in_sizes, int n_in,
                              void* d_out, int out_size, void* d_ws, size_t ws_size,
                              hipStream_t stream) {
  const float* inputs     = (const float*)d_in[0];
  const float* init_state = (const float*)d_in[1];
  const float* noise      = (const float*)d_in[2];
  const float* wih        = (const float*)d_in[3];
  const float* whh        = (const float*)d_in[4];
  const float* bias       = (const float*)d_in[5];
  float* out = (float*)d_out;
  unsigned int* flags = (unsigned int*)d_ws;  // 8 groups x 32 slices

  // d_ws is poisoned 0xAA before every launch; flags must start at 0
  hipMemsetAsync(flags, 0, 256 * sizeof(unsigned int), stream);
  rnn_scan_kernel<<<dim3(256), dim3(256), 0, stream>>>(
      inputs, init_state, noise, wih, whh, bias, out, flags);
}

// Round 2
// 2834.853 us; speedup vs baseline: 5.8426x; 5.8426x over previous
//
#include <hip/hip_runtime.h>

#define T_STEPS 512
#define B_SZ    128
#define H_SZ    1024

typedef __bf16 bf16x8 __attribute__((ext_vector_type(8)));
typedef float  f32x4  __attribute__((ext_vector_type(4)));
typedef float  f32x2  __attribute__((ext_vector_type(2)));

__device__ __forceinline__ void split_bf16(float x, __bf16& hi, __bf16& lo) {
  hi = (__bf16)x;
  lo = (__bf16)(x - (float)hi);
}

// Write-through store (sc0 sc1): bypasses L1/L2 to the agent coherence point
// (Infinity Cache) so consumers on other XCDs can see it without any L2
// writeback fence. Inline asm is NOT tracked by the compiler waitcnt pass --
// must pair with explicit s_waitcnt vmcnt(0) before signaling.
__device__ __forceinline__ void store_x2_wt(float* p, f32x2 v) {
  asm volatile("global_store_dwordx2 %0, %1, off sc0 sc1" :: "v"(p), "v"(v) : "memory");
}
__device__ __forceinline__ void wait_vm0() {
  asm volatile("s_waitcnt vmcnt(0)" ::: "memory");
}

// 256 WGs x 256 threads, persistent. 8 groups (16 batches each) x 32 column
// slices (32 cols each). W_hh slice lives in VGPRs as pre-split bf16 B-frags.
// Cross-WG protocol: each out row is written exactly once before any read, so
// plain cached A-loads can never see a stale line; only the producer side
// needs write-through + flag publication. No cache-maintenance fences at all.
__global__ __launch_bounds__(256, 1)
void rnn_scan_kernel(const float* __restrict__ inputs,
                     const float* __restrict__ init_state,
                     const float* __restrict__ noise,
                     const float* __restrict__ wih,
                     const float* __restrict__ whh,
                     const float* __restrict__ bias,
                     float* __restrict__ out,
                     unsigned int* __restrict__ flags) {
  constexpr float kAlpha = 0.2f;
  constexpr float kBeta  = 0.8f;
  constexpr float kSigma = 0.15811388300841897f;  // sqrt(2/alpha)*0.05

  const int wg   = blockIdx.x;
  const int g    = wg & 7;    // group: blockIdx%8 -> XCD-affine if round-robin
  const int s    = wg >> 3;   // column slice 0..31
  const int b0   = g << 4;    // first batch of group
  const int j0   = s << 5;    // first column of slice
  const int tid  = threadIdx.x;
  const int wave = tid >> 6;
  const int lane = tid & 63;
  const int jn   = lane & 15;         // MFMA m/n lane index
  const int kq   = (lane >> 4) << 3;  // MFMA k quad offset 0/8/16/24

  __shared__ float cred[4][2][16][17];  // per-wave partial C, padded

  // update-phase mapping: thread -> (batch b_l, column pair jp)
  const int b_l = tid >> 4;
  const int jp  = tid & 15;
  const int jj  = j0 + (jp << 1);
  const int gb  = b0 + b_l;

  const float w0e = wih[jj],        w0o = wih[jj + 1];
  const float w1e = wih[H_SZ + jj], w1o = wih[H_SZ + jj + 1];
  const float be  = bias[jj],       bo  = bias[jj + 1];

  // state kept in registers for this thread's two elements
  float he = init_state[gb * H_SZ + jj];
  float ho = init_state[gb * H_SZ + jj + 1];
  { f32x2 v; v[0] = he; v[1] = ho; store_x2_wt(&out[gb * H_SZ + jj], v); }

  // ---- build static B fragments: W_hh[k in wave's 256-range][32 cols] ----
  bf16x8 Bh[8][2], Bl[8][2];
  #pragma unroll
  for (int i = 0; i < 8; ++i) {
    const int kb = (wave << 8) + (i << 5) + kq;
    #pragma unroll
    for (int jt = 0; jt < 2; ++jt) {
      const int jc = j0 + (jt << 4) + jn;
      bf16x8 vh, vl;
      #pragma unroll
      for (int u = 0; u < 8; ++u) {
        const float wv = whh[(kb + u) * H_SZ + jc];
        __bf16 hh, ll; split_bf16(wv, hh, ll);
        vh[u] = hh; vl[u] = ll;
      }
      Bh[i][jt] = vh; Bl[i][jt] = vl;
    }
  }

  wait_vm0();       // row-0 write-through stores acked at coherence point
  __syncthreads();
  if (tid == 0) {
    __hip_atomic_store(&flags[(g << 5) + s], 1u,
                       __ATOMIC_RELAXED, __HIP_MEMORY_SCOPE_AGENT);
  }

  const size_t BH = (size_t)B_SZ * H_SZ;

  for (int t = 0; t < T_STEPS; ++t) {
    // prefetch drive operands (state-independent) before the sync point
    f32x2 nz  = *(const f32x2*)&noise[t * BH + gb * H_SZ + jj];
    f32x2 inp = *(const f32x2*)&inputs[(t * B_SZ + gb) * 2];

    // wait for all 32 slices of state t (flags are monotonic step counters)
    {
      const unsigned int target = (unsigned int)(t + 1);
      int spins = 0;
      bool ok;
      do {
        unsigned int v = target;
        if (lane < 32)
          v = __hip_atomic_load(&flags[(g << 5) + lane],
                                __ATOMIC_RELAXED, __HIP_MEMORY_SCOPE_AGENT);
        ok = __all(v >= target);
        if (!ok) { __builtin_amdgcn_s_sleep(1); if (++spins > (1 << 24)) break; }
      } while (!ok);
    }
    // compiler-only barrier: don't hoist the A loads above the spin.
    // No cache maintenance needed: row t is written exactly once (via
    // write-through) before any read, so no stale copy can exist.
    asm volatile("" ::: "memory");

    // ---- MFMA over this wave's K quarter: out[16,32] partial ----
    f32x4 acc0 = {0.f, 0.f, 0.f, 0.f}, acc1 = {0.f, 0.f, 0.f, 0.f};
    const float* arow = out + t * BH + (size_t)(b0 + jn) * H_SZ + (wave << 8) + kq;
    #pragma unroll
    for (int i = 0; i < 8; ++i) {
      f32x4 v0 = *(const f32x4*)(arow + (i << 5));
      f32x4 v1 = *(const f32x4*)(arow + (i << 5) + 4);
      bf16x8 ah, al;
      #pragma unroll
      for (int u = 0; u < 4; ++u) {
        const float r0 = fmaxf(v0[u], 0.f);
        const float r1 = fmaxf(v1[u], 0.f);
        __bf16 h0, l0, h1, l1;
        split_bf16(r0, h0, l0); split_bf16(r1, h1, l1);
        ah[u] = h0; al[u] = l0; ah[u + 4] = h1; al[u + 4] = l1;
      }
      acc0 = __builtin_amdgcn_mfma_f32_16x16x32_bf16(ah, Bh[i][0], acc0, 0, 0, 0);
      acc1 = __builtin_amdgcn_mfma_f32_16x16x32_bf16(ah, Bh[i][1], acc1, 0, 0, 0);
      acc0 = __builtin_amdgcn_mfma_f32_16x16x32_bf16(al, Bh[i][0], acc0, 0, 0, 0);
      acc1 = __builtin_amdgcn_mfma_f32_16x16x32_bf16(al, Bh[i][1], acc1, 0, 0, 0);
      acc0 = __builtin_amdgcn_mfma_f32_16x16x32_bf16(ah, Bl[i][0], acc0, 0, 0, 0);
      acc1 = __builtin_amdgcn_mfma_f32_16x16x32_bf16(ah, Bl[i][1], acc1, 0, 0, 0);
    }

    // ---- 4-wave reduction via LDS ----
    #pragma unroll
    for (int r = 0; r < 4; ++r) {
      const int br = ((lane >> 4) << 2) + r;  // C row = batch
      cred[wave][0][br][jn] = acc0[r];
      cred[wave][1][br][jn] = acc1[r];
    }
    __syncthreads();

    // ---- state update for this thread's (b_l, jj/jj+1) ----
    const int jt = jp >> 3;
    const int c0 = (jp << 1) & 15;
    const float accE = cred[0][jt][b_l][c0]     + cred[1][jt][b_l][c0]
                     + cred[2][jt][b_l][c0]     + cred[3][jt][b_l][c0];
    const float accO = cred[0][jt][b_l][c0 + 1] + cred[1][jt][b_l][c0 + 1]
                     + cred[2][jt][b_l][c0 + 1] + cred[3][jt][b_l][c0 + 1];
    const float de = fmaf(inp[0], w0e, fmaf(inp[1], w1e, fmaf(kSigma, nz[0], be)));
    const float dq = fmaf(inp[0], w0o, fmaf(inp[1], w1o, fmaf(kSigma, nz[1], bo)));
    he = kBeta * he + kAlpha * (accE + de);
    ho = kBeta * ho + kAlpha * (accO + dq);
    { f32x2 v; v[0] = he; v[1] = ho;
      store_x2_wt(&out[(t + 1) * BH + gb * H_SZ + jj], v); }

    wait_vm0();       // this thread's state stores acked at coherence point
    __syncthreads();  // all threads of WG done storing + cred reads done
    if (tid == 0) {
      __hip_atomic_store(&flags[(g << 5) + s], (unsigned int)(t + 2),
                         __ATOMIC_RELAXED, __HIP_MEMORY_SCOPE_AGENT);
    }
  }
}

extern "C" void kernel_launch(void* const* d_in, const int* in_sizes, int n_in,
                              void* d_out, int out_size, void* d_ws, size_t ws_size,
                              hipStream_t stream) {
  const float* inputs     = (const float*)d_in[0];
  const float* init_state = (const float*)d_in[1];
  const float* noise      = (const float*)d_in[2];
  const float* wih        = (const float*)d_in[3];
  const float* whh        = (const float*)d_in[4];
  const float* bias       = (const float*)d_in[5];
  float* out = (float*)d_out;
  unsigned int* flags = (unsigned int*)d_ws;  // 8 groups x 32 slices

  // d_ws is poisoned 0xAA before every launch; flags must start at 0
  hipMemsetAsync(flags, 0, 256 * sizeof(unsigned int), stream);
  rnn_scan_kernel<<<dim3(256), dim3(256), 0, stream>>>(
      inputs, init_state, noise, wih, whh, bias, out, flags);
}